// Round 19
// baseline (86.020 us; speedup 1.0000x reference)
//
#include <hip/hip_runtime.h>

// Problem constants: features [C=32, N], coords [N,3]=(b,h,w),
// output [B=64, C=32, NH=64, NW=256] float32.
#define CC 32
#define BB 64
#define NHH 64
#define NWW 256
#define PLANE (NHH * NWW)        // 16384 cells per batch
#define BSTRIDE (CC * PLANE)     // 524288 floats per batch in out
#define NCELLS (BB * PLANE)      // 1048576 total cells
#define LROW 260                 // LDS row stride (dwords); 1040B rows, 16B-aligned
#define SUB 4                    // sub-tiles (256n) per block -> 4KB read runs

typedef float f32x4 __attribute__((ext_vector_type(4)));
typedef _Float16 f16x8 __attribute__((ext_vector_type(8)));  // 16B

// ---------- Fallback (round-1) direct scatter ----------
__global__ void pss_scatter_direct(const float* __restrict__ features,
                                   const int* __restrict__ coords,
                                   float* __restrict__ out, int N) {
    int n = blockIdx.x * blockDim.x + threadIdx.x;
    if (n >= N) return;
    int b = coords[3 * n + 0];
    int h = coords[3 * n + 1];
    int w = coords[3 * n + 2];
    int base = b * BSTRIDE + h * NWW + w;
#pragma unroll
    for (int c = 0; c < CC; ++c)
        out[base + c * PLANE] = features[c * N + n];
}

// ---------- K-1: zero invmap ----------
__global__ __launch_bounds__(256) void pss_zero(int4* __restrict__ p, int n4) {
    int i = blockIdx.x * blockDim.x + threadIdx.x;
    if (i < n4) p[i] = make_int4(0, 0, 0, 0);
}

// ---------- K1: long-run DMA transpose -> f16 featT, fused invmap ----------
// features [C][N] f32 -> featT [N][C] f16.
// SINGLE-FACTOR vs r18: each block processes SUB=4 consecutive 256-n
// sub-tiles. Per channel-row the block reads 4KB contiguous ACROSS sub-tiles
// (time-adjacent within one block -> DRAM page hits guaranteed, immune to
// XCD block-scheduling scramble), and writes 64KB contiguous featT.
// Granule->BW ladder from the session: 64B->1.5, 128B->2.1, 1KB->3.5,
// sequential->7 TB/s. This probes the 1KB->4KB step.
__global__ __launch_bounds__(256) void pss_transpose_f16_lr(
        const float* __restrict__ features, const int* __restrict__ coords,
        f16x8* __restrict__ featT, int* __restrict__ invmap, int N) {
    __shared__ float lds[CC * LROW];  // 33280 B

    int t = threadIdx.x;
    int lane = t & 63;
    int w = t >> 6;
    int nb = blockIdx.x * (256 * SUB);

#pragma unroll
    for (int s = 0; s < SUB; ++s) {
        int n0 = nb + 256 * s;
        if (n0 >= N) break;  // block-uniform

        if (s > 0) __syncthreads();  // prev sub-tile's LDS readers done

        // Fused invmap scatter (random 4B into 4MB, L3-absorbed).
        int n = n0 + t;
        if (n < N) {
            int b = coords[3 * n + 0];
            int h = coords[3 * n + 1];
            int ww = coords[3 * n + 2];
            invmap[b * PLANE + h * NWW + ww] = n + 1;
        }

        // Load phase: wave w owns channel rows c = 8w .. 8w+7.
        if (n0 + 256 <= N) {
            // Direct global->LDS DMA, 1KB per issue. Consecutive s are
            // time-adjacent 1KB runs of the same channel row -> page hits.
#pragma unroll
            for (int r = 0; r < 8; ++r) {
                int c = 8 * w + r;
                const float* gp = &features[(size_t)c * N + n0 + 4 * lane];
                __builtin_amdgcn_global_load_lds(
                    (const __attribute__((address_space(1))) void*)gp,
                    (__attribute__((address_space(3))) void*)&lds[c * LROW],
                    16, 0, 0);
            }
        } else {
            // Tail sub-tile: guarded path (N%4==0 -> whole-quad guard).
#pragma unroll
            for (int r = 0; r < 8; ++r) {
                int c = 8 * w + r;
                int nn = n0 + 4 * lane;
                f32x4 v = (f32x4){0.f, 0.f, 0.f, 0.f};
                if (nn < N)
                    v = *(const f32x4*)&features[(size_t)c * N + nn];
                *(f32x4*)&lds[c * LROW + 4 * lane] = v;
            }
        }

        __syncthreads();  // drains vmcnt(0): DMA complete, LDS visible

        // Store phase: transposed read + f16 pack + linear 16B store.
        // flat f16x8 index within sub-tile = t + 256*j (0..1023);
        // nl = idx>>2 (local n), g = idx&3 (channel group of 8).
#pragma unroll
        for (int j = 0; j < 4; ++j) {
            int idx = t + 256 * j;
            int nl = idx >> 2;
            int g = idx & 3;
            if (n0 + nl < N) {
                f16x8 hv;
#pragma unroll
                for (int e = 0; e < 8; ++e)
                    hv[e] = (_Float16)lds[(8 * g + e) * LROW + nl];
                featT[(size_t)n0 * 4 + idx] = hv;  // block walks 64KB contiguous
            }
        }
    }
}

// ---------- K2: gather f16 featT rows per cell, emit out coalesced ----------
// featT rows random but L3-resident (57.6 MB). out stores nontemporal
// (write-once 128MB stream; don't evict featT/features).
__global__ __launch_bounds__(256) void pss_gather_emit_f16(
        const f16x8* __restrict__ featT, const int* __restrict__ invmap,
        float* __restrict__ out) {
    __shared__ float lds[NWW * (CC + 1)];  // 256 * 33 floats

    int row = blockIdx.x;          // 0 .. B*NH-1  (row = b*NHH + h)
    int b = row / NHH;
    int h = row % NHH;
    int t = threadIdx.x;           // 0..255 = w

    int inv = invmap[(size_t)row * NWW + t];  // coalesced 1KB per block

    if (inv > 0) {
        const f16x8* src = featT + (size_t)(inv - 1) * 4;  // 64B row = 1 line
#pragma unroll
        for (int k = 0; k < 4; ++k) {
            f16x8 hv = src[k];
#pragma unroll
            for (int e = 0; e < 8; ++e)
                lds[t * (CC + 1) + 8 * k + e] = (float)hv[e];
        }
    } else {
#pragma unroll
        for (int k = 0; k < CC; ++k)
            lds[t * (CC + 1) + k] = 0.0f;
    }

    __syncthreads();

    size_t obase = (size_t)b * BSTRIDE + (size_t)h * NWW + t;
#pragma unroll
    for (int c = 0; c < CC; ++c) {
        float v = lds[t * (CC + 1) + c];  // bank (t+c)%32 -> conflict-free
        __builtin_nontemporal_store(v, &out[obase + (size_t)c * PLANE]);
    }
}

extern "C" void kernel_launch(void* const* d_in, const int* in_sizes, int n_in,
                              void* d_out, int out_size, void* d_ws, size_t ws_size,
                              hipStream_t stream) {
    const float* features = (const float*)d_in[0];
    const int* coords = (const int*)d_in[1];
    float* out = (float*)d_out;
    const int N = in_sizes[1] / 3;

    const size_t invmap_bytes = (size_t)NCELLS * sizeof(int);        // 4 MiB
    const size_t featT_bytes = (size_t)N * CC * sizeof(_Float16);    // ~57.6 MB

    if (ws_size < invmap_bytes + featT_bytes) {
        // Fallback: direct scatter (correct, slower).
        (void)hipMemsetAsync(d_out, 0, (size_t)out_size * sizeof(float), stream);
        int blocks = (N + 255) / 256;
        pss_scatter_direct<<<blocks, 256, 0, stream>>>(features, coords, out, N);
        return;
    }

    int* invmap = (int*)d_ws;
    f16x8* featT = (f16x8*)((char*)d_ws + invmap_bytes);

    // Zero invmap (0 == empty cell).
    pss_zero<<<(NCELLS / 4 + 255) / 256, 256, 0, stream>>>((int4*)invmap,
                                                           NCELLS / 4);

    int blocks = (N + 256 * SUB - 1) / (256 * SUB);  // 879 for N=900000
    pss_transpose_f16_lr<<<blocks, 256, 0, stream>>>(features, coords, featT,
                                                     invmap, N);

    pss_gather_emit_f16<<<BB * NHH, 256, 0, stream>>>(featT, invmap, out);
}